// Round 8
// baseline (349.554 us; speedup 1.0000x reference)
//
#include <hip/hip_runtime.h>

#define TPB 256      // expand_out block
#define GTPB 512     // topk_row block: 512 thr x 16 elems -> fb[8], no spill
#define ROWN 8192
#define CMAX 1024   // per-row candidate cap (r12-r18 proven never hit)
#define EPS_TINY 1.1754943508222875e-38f   // np.finfo(np.float32).tiny

__device__ __forceinline__ unsigned rotl32(unsigned x, int r) {
  return (x << r) | (x >> (32 - r));
}

// threefry2x32, key (0,42), partitionable counters: ctr=(0,idx), bits = x0^x1.
// Verified on-device (r11 decode; r12-r18 absmax 0.0).
__device__ __forceinline__ unsigned tf_pxor(unsigned idx) {
  const unsigned ks0 = 0u, ks1 = 42u, ks2 = 0x1BD11BDAu ^ 0u ^ 42u;
  unsigned x0 = ks0;
  unsigned x1 = idx + ks1;
#define TF4(a,b,cc,d) \
  x0 += x1; x1 = rotl32(x1,(a));  x1 ^= x0; \
  x0 += x1; x1 = rotl32(x1,(b));  x1 ^= x0; \
  x0 += x1; x1 = rotl32(x1,(cc)); x1 ^= x0; \
  x0 += x1; x1 = rotl32(x1,(d));  x1 ^= x0;
  TF4(13,15,26,6)   x0 += ks1; x1 += ks2 + 1u;
  TF4(17,29,16,24)  x0 += ks2; x1 += ks0 + 2u;
  TF4(13,15,26,6)   x0 += ks0; x1 += ks1 + 3u;
  TF4(17,29,16,24)  x0 += ks1; x1 += ks2 + 4u;
  TF4(13,15,26,6)   x0 += ks2; x1 += ks0 + 5u;
#undef TF4
  return x0 ^ x1;
}

// EXACT jax gumbel (precise ocml logf) — candidates only, bit-exact.
__device__ __forceinline__ float gumbel_of(unsigned idx) {
  const unsigned bits = tf_pxor(idx);
  float u = __uint_as_float((bits >> 9) | 0x3f800000u) - 1.0f;
  u = u + EPS_TINY;
  u = fmaxf(EPS_TINY, u);
  return -logf(-logf(u));
}

// APPROX gumbel for the filter pass: |err| <= ~2e-4 (proven r15-r18).
__device__ __forceinline__ float approx_gumbel(unsigned bits) {
  float u = __uint_as_float((bits >> 9) | 0x3f800000u) - 1.0f;
  u = u + EPS_TINY;
  u = fmaxf(EPS_TINY, u);
  float t;
  if (u >= 0.75f) {
    const float v = 1.0f - u;   // exact (Sterbenz)
    t = v * (1.0f + v * (0.5f + v * (0.33333334f + v * (0.25f + v * 0.2f))));
  } else {
    t = -0.69314718f * __log2f(u);
  }
  return -0.69314718f * __log2f(t);
}

// Monotone 16-bit sort key of bf16-truncated float: x<=y => key(x)<=key(y).
// (f finite here: |score|<=16, gumbel in (-5,~30), no NaN/inf.)
__device__ __forceinline__ unsigned key16_of(float x) {
  const unsigned b = __float_as_uint(x) >> 16;
  return (b & 0x8000u) ? (0xFFFFu & ~b) : (b | 0x8000u);
}

// =====================================================================
// Fused kernel: one block per (rep, b, e) ROW. grid=2048, 512 thr
// (8 waves), 16 elems/thread -> fb[8] packed keys + cfr/khr/ek/idxr[2].
// Live set ~30 regs << 64-reg budget at (512,8): the r7 spills
// (WRITE_SIZE 12.5MB, scratch-capped occupancy 67%) are removed by
// GEOMETRY, not packing. 4 blocks/CU x 8 waves = 32 waves/CU.
// Same f(n), same block max, same integer bisect counts -> same theta /
// ktheta / candidate SET as r7 (absmax 0.0). Candidate order & Z
// rounding differ ~1e-7 — the perturbation class proven harmless across
// r0/r1/r4/r6/r7. Dynamics/selection bodies identical to r7, reduction
// arrays widened 4 -> 8 waves (same proven barrier pattern).
// =====================================================================
__global__ __launch_bounds__(GTPB, 8)
void topk_row(const void* __restrict__ scores_raw, int* __restrict__ selws) {
  const int t    = threadIdx.x;      // 0..511
  const int lane = t & 63;
  const int wave = t >> 6;           // 0..7

  // XCD grouping: all 8 rows (4e x 2rep) of input panel b land on one XCD.
  const int i   = blockIdx.x;       // 0..2047
  const int xcd = i & 7;
  const int k   = i >> 3;           // 0..255
  const int e   = k & 3;
  const int q   = k >> 2;           // 0..63
  const int b   = xcd * 32 + (q & 31);
  const int rep = q >> 5;
  const int r   = rep * 1024 + b * 4 + e;
  const unsigned gbase = (unsigned)r * (unsigned)ROWN;

  __shared__ int   candIdx[CMAX];     // 4 KB
  __shared__ float redM[8];
  __shared__ float redZ[8];
  __shared__ int   wtot[13][8];
  __shared__ float bV[2][8];
  __shared__ int   bI[2][8];
  __shared__ int   f32flag;

  // ---- input dtype autodetect (4 KB prefix; proven r11-r18) ----
  if (t == 0) f32flag = 0;
  __syncthreads();
  {
    const unsigned* w = (const unsigned*)scores_raw;
    bool bad = false;
#pragma unroll
    for (int p = 0; p < 2; ++p) {
      const unsigned x = w[t + 512 * p];
      const float flo = __uint_as_float((x & 0xFFFFu) << 16);
      const float fhi = __uint_as_float(x & 0xFFFF0000u);
      if (!(fabsf(flo) <= 16.0f) || !(fabsf(fhi) <= 16.0f)) bad = true;
    }
    if (bad) f32flag = 1;
  }
  __syncthreads();
  const bool in_f32 = (f32flag != 0);

  // ================= phase 1: gen -> theta -> compact (single row) ======
  const size_t ebase0 = ((size_t)b * ROWN + (size_t)t) * 4 + (size_t)e;
  unsigned fb[8];                     // 16 filter keys, 2 per reg
  float m = -3.4e38f;
  if (in_f32) {
    const float* sp = (const float*)scores_raw;
#pragma unroll
    for (int j = 0; j < 16; ++j) {
      const float fj = sp[ebase0 + (size_t)(512 * j) * 4]
                     + approx_gumbel(tf_pxor(gbase + (unsigned)(t + 512 * j)));
      m = fmaxf(m, fj);
      const unsigned kk = key16_of(fj);
      if (j & 1) fb[j >> 1] |= kk << 16; else fb[j >> 1] = kk;
    }
  } else {
    const unsigned short* sp = (const unsigned short*)scores_raw;
#pragma unroll
    for (int j = 0; j < 16; ++j) {
      const float fj = __uint_as_float(((unsigned)sp[ebase0 + (size_t)(512 * j) * 4]) << 16)
                     + approx_gumbel(tf_pxor(gbase + (unsigned)(t + 512 * j)));
      m = fmaxf(m, fj);
      const unsigned kk = key16_of(fj);
      if (j & 1) fb[j >> 1] |= kk << 16; else fb[j >> 1] = kk;
    }
  }

  // block max (f32; max over same multiset -> identical value)
#pragma unroll
  for (int off = 32; off >= 1; off >>= 1) m = fmaxf(m, __shfl_xor(m, off));
  if (lane == 0) redM[wave] = m;
  __syncthreads();
#pragma unroll
  for (int w = 0; w < 8; ++w) m = fmaxf(m, redM[w]);

  // bisect theta33 (12 iters, f32 mids, counts in key domain — identical)
  float lo = m - 25.0f, hi = m;
#pragma unroll 1
  for (int itb = 0; itb < 12; ++itb) {
    const float mid = 0.5f * (lo + hi);
    const unsigned kmid = key16_of(mid);
    int c = 0;
#pragma unroll
    for (int h = 0; h < 8; ++h) {
      c += ((fb[h] & 0xFFFFu) > kmid) ? 1 : 0;
      c += ((fb[h] >> 16) > kmid) ? 1 : 0;
    }
#pragma unroll
    for (int off = 32; off >= 1; off >>= 1) c += __shfl_xor(c, off);
    if (lane == 0) wtot[itb][wave] = c;
    __syncthreads();
    int tot = 0;
#pragma unroll
    for (int w = 0; w < 8; ++w) tot += wtot[itb][w];
    if (tot >= 33) lo = mid; else hi = mid;
  }
  const float theta = lo - 2.34f;          // lo < f*_(33) via monotone key
  const unsigned ktheta = key16_of(theta); // compact predicate: key >= ktheta

  // compact candidate indices (deterministic prefix order, >= superset)
  int cj = 0;
#pragma unroll
  for (int h = 0; h < 8; ++h) {
    cj += ((fb[h] & 0xFFFFu) >= ktheta) ? 1 : 0;
    cj += ((fb[h] >> 16) >= ktheta) ? 1 : 0;
  }
  int incv = cj;
#pragma unroll
  for (int off = 1; off < 64; off <<= 1) {
    const int v = __shfl_up(incv, off);
    if (lane >= off) incv += v;
  }
  if (lane == 63) wtot[12][wave] = incv;
  __syncthreads();
  int base = 0;
  for (int w = 0; w < wave; ++w) base += wtot[12][w];
  int cnt = 0;
#pragma unroll
  for (int w = 0; w < 8; ++w) cnt += wtot[12][w];
  if (cnt > CMAX) cnt = CMAX;
  int o = base + incv - cj;
#pragma unroll
  for (int j = 0; j < 16; ++j) {
    const unsigned kj = (j & 1) ? (fb[j >> 1] >> 16) : (fb[j >> 1] & 0xFFFFu);
    if (kj >= ktheta) {
      if (o < CMAX) candIdx[o] = t + 512 * j;
      ++o;
    }
  }
  __syncthreads();   // candIdx visible to whole block

  // ================= phase 2: block-wide dynamics (2 chunks of 512) =====
  float cfr[2], khr[2];
  int   idxr[2];
#pragma unroll
  for (int p = 0; p < 2; ++p) {
    cfr[p] = -3.0e38f; khr[p] = -3.0e38f; idxr[p] = 0x7FFFFFFF;
    if (512 * p < cnt) {               // block-uniform chunk skip
      const int ci = t + 512 * p;
      if (ci < cnt) {
        const int n = candIdx[ci];
        const size_t ei = ((size_t)b * ROWN + (size_t)n) * 4 + (size_t)e;
        float sc;
        if (in_f32) sc = ((const float*)scores_raw)[ei];
        else sc = __uint_as_float(((unsigned)((const unsigned short*)scores_raw)[ei]) << 16);
        cfr[p] = sc + gumbel_of(gbase + (unsigned)n);   // bit-exact
        khr[p] = 0.0f;
        idxr[p] = n;
      }
    }
  }

  // 32 dynamics iterations; fast-math branchless body (r6/r7, absmax 0.0).
#pragma unroll 1
  for (int it = 0; it < 32; ++it) {
    float m2 = -3.4e38f;
#pragma unroll
    for (int p = 0; p < 2; ++p)
      if (512 * p < cnt) m2 = fmaxf(m2, cfr[p]);
#pragma unroll
    for (int off = 32; off >= 1; off >>= 1) m2 = fmaxf(m2, __shfl_xor(m2, off));
    if (lane == 0) redM[wave] = m2;
    __syncthreads();
#pragma unroll
    for (int w = 0; w < 8; ++w) m2 = fmaxf(m2, redM[w]);

    float ek[2];
    float Z = 0.0f;
#pragma unroll
    for (int p = 0; p < 2; ++p) {
      float ev = 0.0f;
      if (512 * p < cnt) {
        // filler cfr=-3e38: (cfr-m2)*10 -> -inf -> ev = 0 (exact no-op)
        ev = __expf((cfr[p] - m2) * 10.0f);
        Z += ev;
      }
      ek[p] = ev;
    }
#pragma unroll
    for (int off = 32; off >= 1; off >>= 1) Z += __shfl_xor(Z, off);
    if (lane == 0) redZ[wave] = Z;
    __syncthreads();
    // fixed deterministic order
    Z = ((redZ[0] + redZ[1]) + (redZ[2] + redZ[3]))
      + ((redZ[4] + redZ[5]) + (redZ[6] + redZ[7]));

    const float rz = __builtin_amdgcn_rcpf(Z);       // Z in [1,cnt]; ~1e-7 rel
#pragma unroll
    for (int p = 0; p < 2; ++p) {
      if (512 * p < cnt) {
        const float pp = ek[p] * rz;                 // 0 for inactive lanes
        khr[p] += pp;                                // += 0 is bitwise no-op
        cfr[p] += __logf(fmaxf(1.0f - pp, EPS_TINY));
      }
    }
  }

  // top-32 of khot, lowest-n tie-break, block-wide (double-buffered slots)
#pragma unroll 1
  for (int pass = 0; pass < 32; ++pass) {
    float bv = -3.4e38f; int bi = 0x7FFFFFFF;
#pragma unroll
    for (int p = 0; p < 2; ++p) {
      if (512 * p < cnt) {
        const float v = khr[p]; const int ix = idxr[p];
        if (v > bv || (v == bv && ix < bi)) { bv = v; bi = ix; }
      }
    }
#pragma unroll
    for (int off = 32; off >= 1; off >>= 1) {
      const float ov = __shfl_xor(bv, off);
      const int   oi = __shfl_xor(bi, off);
      if (ov > bv || (ov == bv && oi < bi)) { bv = ov; bi = oi; }
    }
    if (lane == 0) { bV[pass & 1][wave] = bv; bI[pass & 1][wave] = bi; }
    __syncthreads();
#pragma unroll
    for (int w = 0; w < 8; ++w) {
      const float ov = bV[pass & 1][w]; const int oi = bI[pass & 1][w];
      if (ov > bv || (ov == bv && oi < bi)) { bv = ov; bi = oi; }
    }
    if (t == 0) selws[r * 32 + pass] = bi;
#pragma unroll
    for (int p = 0; p < 2; ++p)
      if (512 * p < cnt && idxr[p] == bi) khr[p] = -3.0e38f;
  }
}

// =====================================================================
// Kernel 2: bitmap expand -> coalesced float4 slab (unchanged, proven).
// =====================================================================
__global__ __launch_bounds__(TPB)
void expand_out(const int* __restrict__ selws, float4* __restrict__ out4) {
  const int t   = threadIdx.x;
  const int blk = blockIdx.x;        // 0..2047
  const int grp = blk >> 2;          // rep*256 + b
  const int s   = blk & 3;           // n-slice of 2048
  const int rep = grp >> 8;
  const int b   = grp & 255;

  __shared__ unsigned ebm[4 * 256];  // 4 e-planes x 8192 bits
#pragma unroll
  for (int p = 0; p < 4; ++p) ebm[t + 256 * p] = 0u;
  __syncthreads();
  if (t < 4) {
    const int r = rep * 1024 + b * 4 + t;
#pragma unroll 1
    for (int p = 0; p < 32; ++p) {
      const int ix = selws[r * 32 + p];
      ebm[t * 256 + (ix >> 5)] |= (1u << (ix & 31));
    }
  }
  __syncthreads();

  const size_t obase = (size_t)grp * ROWN;
#pragma unroll
  for (int j = 0; j < 8; ++j) {
    const int n = s * 2048 + t + 256 * j;
    float4 v;
    v.x = ((ebm[0 * 256 + (n >> 5)] >> (n & 31)) & 1u) ? 1.0f : 0.0f;
    v.y = ((ebm[1 * 256 + (n >> 5)] >> (n & 31)) & 1u) ? 1.0f : 0.0f;
    v.z = ((ebm[2 * 256 + (n >> 5)] >> (n & 31)) & 1u) ? 1.0f : 0.0f;
    v.w = ((ebm[3 * 256 + (n >> 5)] >> (n & 31)) & 1u) ? 1.0f : 0.0f;
    out4[obase + (size_t)n] = v;
  }
}

extern "C" void kernel_launch(void* const* d_in, const int* in_sizes, int n_in,
                              void* d_out, int out_size, void* d_ws, size_t ws_size,
                              hipStream_t stream) {
  const void* scores = d_in[0];      // dtype autodetected in-kernel
  int* selws = (int*)d_ws;           // 2048 rows x 32 ints = 256 KB
  topk_row<<<dim3(2048), dim3(GTPB), 0, stream>>>(scores, selws);
  expand_out<<<dim3(2048), dim3(TPB), 0, stream>>>(selws, (float4*)d_out);
}

// Round 9
// 256.748 us; speedup vs baseline: 1.3615x; 1.3615x over previous
//
#include <hip/hip_runtime.h>

#define TPB 256
#define ROWN 8192
#define CMAX 1024   // per-row candidate cap (r12-r18 proven never hit)
#define EPS_TINY 1.1754943508222875e-38f   // np.finfo(np.float32).tiny

__device__ __forceinline__ unsigned rotl32(unsigned x, int r) {
  return (x << r) | (x >> (32 - r));
}

// threefry2x32, key (0,42), partitionable counters: ctr=(0,idx), bits = x0^x1.
// Verified on-device (r11 decode; r12-r18 absmax 0.0).
__device__ __forceinline__ unsigned tf_pxor(unsigned idx) {
  const unsigned ks0 = 0u, ks1 = 42u, ks2 = 0x1BD11BDAu ^ 0u ^ 42u;
  unsigned x0 = ks0;
  unsigned x1 = idx + ks1;
#define TF4(a,b,cc,d) \
  x0 += x1; x1 = rotl32(x1,(a));  x1 ^= x0; \
  x0 += x1; x1 = rotl32(x1,(b));  x1 ^= x0; \
  x0 += x1; x1 = rotl32(x1,(cc)); x1 ^= x0; \
  x0 += x1; x1 = rotl32(x1,(d));  x1 ^= x0;
  TF4(13,15,26,6)   x0 += ks1; x1 += ks2 + 1u;
  TF4(17,29,16,24)  x0 += ks2; x1 += ks0 + 2u;
  TF4(13,15,26,6)   x0 += ks0; x1 += ks1 + 3u;
  TF4(17,29,16,24)  x0 += ks1; x1 += ks2 + 4u;
  TF4(13,15,26,6)   x0 += ks2; x1 += ks0 + 5u;
#undef TF4
  return x0 ^ x1;
}

// EXACT jax gumbel (precise ocml logf) — candidates only, bit-exact.
__device__ __forceinline__ float gumbel_of(unsigned idx) {
  const unsigned bits = tf_pxor(idx);
  float u = __uint_as_float((bits >> 9) | 0x3f800000u) - 1.0f;
  u = u + EPS_TINY;
  u = fmaxf(EPS_TINY, u);
  return -logf(-logf(u));
}

// APPROX gumbel for the filter pass: |err| <= ~2e-4 (proven r15-r18).
__device__ __forceinline__ float approx_gumbel(unsigned bits) {
  float u = __uint_as_float((bits >> 9) | 0x3f800000u) - 1.0f;
  u = u + EPS_TINY;
  u = fmaxf(EPS_TINY, u);
  float t;
  if (u >= 0.75f) {
    const float v = 1.0f - u;   // exact (Sterbenz)
    t = v * (1.0f + v * (0.5f + v * (0.33333334f + v * (0.25f + v * 0.2f))));
  } else {
    t = -0.69314718f * __log2f(u);
  }
  return -0.69314718f * __log2f(t);
}

// Monotone 16-bit sort key of bf16-truncated float: x<=y => key(x)<=key(y).
// (f finite here: |score|<=16, gumbel in (-5,~30), no NaN/inf.)
__device__ __forceinline__ unsigned key16_of(float x) {
  const unsigned b = __float_as_uint(x) >> 16;
  return (b & 0x8000u) ? (0xFFFFu & ~b) : (b | 0x8000u);
}

// =====================================================================
// Fused kernel: one block per (rep, b, e) ROW. grid=2048, 256 thr.
// r7 geometry byte-for-byte (r8 proved widening the block doubles the
// per-row reduction/selection cost — never trade elems/thread for
// threads/row here). The r7 residual spill (~6 regs, 12.5MB scratch,
// occupancy capped 67%) is removed by RECOMPUTATION, not geometry:
//   - ek[4] dropped: __expf recomputed at the update (bit-identical pp)
//   - idxr[4] dropped: index re-read from candIdx LDS in selection
//     (inactive lanes carry khot=-3e38 and can never win a pass)
// Everything else identical to r7 (absmax 0.0 proven).
// =====================================================================
__global__ __launch_bounds__(TPB, 8)
void topk_row(const void* __restrict__ scores_raw, int* __restrict__ selws) {
  const int t    = threadIdx.x;
  const int lane = t & 63;
  const int wave = t >> 6;

  // XCD grouping: all 8 rows (4e x 2rep) of input panel b land on one XCD.
  const int i   = blockIdx.x;       // 0..2047
  const int xcd = i & 7;
  const int k   = i >> 3;           // 0..255
  const int e   = k & 3;
  const int q   = k >> 2;           // 0..63
  const int b   = xcd * 32 + (q & 31);
  const int rep = q >> 5;
  const int r   = rep * 1024 + b * 4 + e;
  const unsigned gbase = (unsigned)r * (unsigned)ROWN;

  __shared__ int   candIdx[CMAX];     // 4 KB
  __shared__ float redM[4];
  __shared__ float redZ[4];
  __shared__ int   wtot[13][4];
  __shared__ float bV[2][4];
  __shared__ int   bI[2][4];
  __shared__ int   f32flag;

  // ---- input dtype autodetect (4 KB prefix; proven r11-r18) ----
  if (t == 0) f32flag = 0;
  __syncthreads();
  {
    const unsigned* w = (const unsigned*)scores_raw;
    bool bad = false;
#pragma unroll
    for (int p = 0; p < 4; ++p) {
      const unsigned x = w[t + 256 * p];
      const float flo = __uint_as_float((x & 0xFFFFu) << 16);
      const float fhi = __uint_as_float(x & 0xFFFF0000u);
      if (!(fabsf(flo) <= 16.0f) || !(fabsf(fhi) <= 16.0f)) bad = true;
    }
    if (bad) f32flag = 1;
  }
  __syncthreads();
  const bool in_f32 = (f32flag != 0);

  // ================= phase 1: gen -> theta -> compact (single row) ======
  const size_t ebase0 = ((size_t)b * ROWN + (size_t)t) * 4 + (size_t)e;
  unsigned fb[16];                    // 32 filter keys, 2 per reg
  float m = -3.4e38f;
  if (in_f32) {
    const float* sp = (const float*)scores_raw;
#pragma unroll
    for (int j = 0; j < 32; ++j) {
      const float fj = sp[ebase0 + (size_t)(256 * j) * 4]
                     + approx_gumbel(tf_pxor(gbase + (unsigned)(t + 256 * j)));
      m = fmaxf(m, fj);
      const unsigned kk = key16_of(fj);
      if (j & 1) fb[j >> 1] |= kk << 16; else fb[j >> 1] = kk;
    }
  } else {
    const unsigned short* sp = (const unsigned short*)scores_raw;
#pragma unroll
    for (int j = 0; j < 32; ++j) {
      const float fj = __uint_as_float(((unsigned)sp[ebase0 + (size_t)(256 * j) * 4]) << 16)
                     + approx_gumbel(tf_pxor(gbase + (unsigned)(t + 256 * j)));
      m = fmaxf(m, fj);
      const unsigned kk = key16_of(fj);
      if (j & 1) fb[j >> 1] |= kk << 16; else fb[j >> 1] = kk;
    }
  }

  // block max (f32, computed before packing)
#pragma unroll
  for (int off = 32; off >= 1; off >>= 1) m = fmaxf(m, __shfl_xor(m, off));
  if (lane == 0) redM[wave] = m;
  __syncthreads();
  m = fmaxf(fmaxf(redM[0], redM[1]), fmaxf(redM[2], redM[3]));

  // bisect theta33 (12 iters, f32 mids, counts in key domain)
  float lo = m - 25.0f, hi = m;
#pragma unroll 1
  for (int itb = 0; itb < 12; ++itb) {
    const float mid = 0.5f * (lo + hi);
    const unsigned kmid = key16_of(mid);
    int c = 0;
#pragma unroll
    for (int h = 0; h < 16; ++h) {
      c += ((fb[h] & 0xFFFFu) > kmid) ? 1 : 0;
      c += ((fb[h] >> 16) > kmid) ? 1 : 0;
    }
#pragma unroll
    for (int off = 32; off >= 1; off >>= 1) c += __shfl_xor(c, off);
    if (lane == 0) wtot[itb][wave] = c;
    __syncthreads();
    const int tot = wtot[itb][0] + wtot[itb][1] + wtot[itb][2] + wtot[itb][3];
    if (tot >= 33) lo = mid; else hi = mid;
  }
  const float theta = lo - 2.34f;          // lo < f*_(33) via monotone key
  const unsigned ktheta = key16_of(theta); // compact predicate: key >= ktheta

  // compact candidate indices (deterministic prefix order, >= superset)
  int cj = 0;
#pragma unroll
  for (int h = 0; h < 16; ++h) {
    cj += ((fb[h] & 0xFFFFu) >= ktheta) ? 1 : 0;
    cj += ((fb[h] >> 16) >= ktheta) ? 1 : 0;
  }
  int incv = cj;
#pragma unroll
  for (int off = 1; off < 64; off <<= 1) {
    const int v = __shfl_up(incv, off);
    if (lane >= off) incv += v;
  }
  if (lane == 63) wtot[12][wave] = incv;
  __syncthreads();
  int base = 0;
  for (int w = 0; w < wave; ++w) base += wtot[12][w];
  int cnt = wtot[12][0] + wtot[12][1] + wtot[12][2] + wtot[12][3];
  if (cnt > CMAX) cnt = CMAX;
  int o = base + incv - cj;
#pragma unroll
  for (int j = 0; j < 32; ++j) {
    const unsigned kj = (j & 1) ? (fb[j >> 1] >> 16) : (fb[j >> 1] & 0xFFFFu);
    if (kj >= ktheta) {
      if (o < CMAX) candIdx[o] = t + 256 * j;
      ++o;
    }
  }
  __syncthreads();   // candIdx visible to whole block

  // ================= phase 2: block-wide dynamics (4 chunks of 256) =====
  float cfr[4], khr[4];
#pragma unroll
  for (int p = 0; p < 4; ++p) {
    cfr[p] = -3.0e38f; khr[p] = -3.0e38f;
    if (256 * p < cnt) {               // block-uniform chunk skip
      const int ci = t + 256 * p;
      if (ci < cnt) {
        const int n = candIdx[ci];
        const size_t ei = ((size_t)b * ROWN + (size_t)n) * 4 + (size_t)e;
        float sc;
        if (in_f32) sc = ((const float*)scores_raw)[ei];
        else sc = __uint_as_float(((unsigned)((const unsigned short*)scores_raw)[ei]) << 16);
        cfr[p] = sc + gumbel_of(gbase + (unsigned)n);   // bit-exact
        khr[p] = 0.0f;
      }
    }
  }

  // 32 dynamics iterations; fast-math branchless body (r6/r7, absmax 0.0).
  // ek[] eliminated: exp recomputed at the update (bit-identical values).
#pragma unroll 1
  for (int it = 0; it < 32; ++it) {
    float m2 = -3.4e38f;
#pragma unroll
    for (int p = 0; p < 4; ++p)
      if (256 * p < cnt) m2 = fmaxf(m2, cfr[p]);
#pragma unroll
    for (int off = 32; off >= 1; off >>= 1) m2 = fmaxf(m2, __shfl_xor(m2, off));
    if (lane == 0) redM[wave] = m2;
    __syncthreads();
    m2 = fmaxf(fmaxf(redM[0], redM[1]), fmaxf(redM[2], redM[3]));

    float Z = 0.0f;
#pragma unroll
    for (int p = 0; p < 4; ++p) {
      if (256 * p < cnt) {
        // filler cfr=-3e38: (cfr-m2)*10 -> -inf -> exp = 0 (exact no-op)
        Z += __expf((cfr[p] - m2) * 10.0f);
      }
    }
#pragma unroll
    for (int off = 32; off >= 1; off >>= 1) Z += __shfl_xor(Z, off);
    if (lane == 0) redZ[wave] = Z;
    __syncthreads();
    Z = (redZ[0] + redZ[1]) + (redZ[2] + redZ[3]);   // fixed deterministic order

    const float rz = __builtin_amdgcn_rcpf(Z);       // Z in [1,cnt]; ~1e-7 rel
#pragma unroll
    for (int p = 0; p < 4; ++p) {
      if (256 * p < cnt) {
        const float pp = __expf((cfr[p] - m2) * 10.0f) * rz;  // recompute, 0 inactive
        khr[p] += pp;                                // += 0 is bitwise no-op
        cfr[p] += __logf(fmaxf(1.0f - pp, EPS_TINY));
      }
    }
  }

  // top-32 of khot, lowest-n tie-break, block-wide (double-buffered slots).
  // idxr[] eliminated: index re-read from candIdx LDS (guarded; inactive
  // lanes have khot=-3e38 and cannot win — real candidates have khot>=0).
#pragma unroll 1
  for (int pass = 0; pass < 32; ++pass) {
    float bv = -3.4e38f; int bi = 0x7FFFFFFF;
#pragma unroll
    for (int p = 0; p < 4; ++p) {
      if (256 * p < cnt) {
        const int ci = t + 256 * p;
        const int ix = (ci < cnt) ? candIdx[ci] : 0x7FFFFFFF;
        const float v = khr[p];
        if (v > bv || (v == bv && ix < bi)) { bv = v; bi = ix; }
      }
    }
#pragma unroll
    for (int off = 32; off >= 1; off >>= 1) {
      const float ov = __shfl_xor(bv, off);
      const int   oi = __shfl_xor(bi, off);
      if (ov > bv || (ov == bv && oi < bi)) { bv = ov; bi = oi; }
    }
    if (lane == 0) { bV[pass & 1][wave] = bv; bI[pass & 1][wave] = bi; }
    __syncthreads();
#pragma unroll
    for (int w = 0; w < 4; ++w) {
      const float ov = bV[pass & 1][w]; const int oi = bI[pass & 1][w];
      if (ov > bv || (ov == bv && oi < bi)) { bv = ov; bi = oi; }
    }
    if (t == 0) selws[r * 32 + pass] = bi;
#pragma unroll
    for (int p = 0; p < 4; ++p) {
      if (256 * p < cnt) {
        const int ci = t + 256 * p;
        if (ci < cnt && candIdx[ci] == bi) khr[p] = -3.0e38f;
      }
    }
  }
}

// =====================================================================
// Kernel 2: bitmap expand -> coalesced float4 slab (unchanged, proven).
// =====================================================================
__global__ __launch_bounds__(TPB)
void expand_out(const int* __restrict__ selws, float4* __restrict__ out4) {
  const int t   = threadIdx.x;
  const int blk = blockIdx.x;        // 0..2047
  const int grp = blk >> 2;          // rep*256 + b
  const int s   = blk & 3;           // n-slice of 2048
  const int rep = grp >> 8;
  const int b   = grp & 255;

  __shared__ unsigned ebm[4 * 256];  // 4 e-planes x 8192 bits
#pragma unroll
  for (int p = 0; p < 4; ++p) ebm[t + 256 * p] = 0u;
  __syncthreads();
  if (t < 4) {
    const int r = rep * 1024 + b * 4 + t;
#pragma unroll 1
    for (int p = 0; p < 32; ++p) {
      const int ix = selws[r * 32 + p];
      ebm[t * 256 + (ix >> 5)] |= (1u << (ix & 31));
    }
  }
  __syncthreads();

  const size_t obase = (size_t)grp * ROWN;
#pragma unroll
  for (int j = 0; j < 8; ++j) {
    const int n = s * 2048 + t + 256 * j;
    float4 v;
    v.x = ((ebm[0 * 256 + (n >> 5)] >> (n & 31)) & 1u) ? 1.0f : 0.0f;
    v.y = ((ebm[1 * 256 + (n >> 5)] >> (n & 31)) & 1u) ? 1.0f : 0.0f;
    v.z = ((ebm[2 * 256 + (n >> 5)] >> (n & 31)) & 1u) ? 1.0f : 0.0f;
    v.w = ((ebm[3 * 256 + (n >> 5)] >> (n & 31)) & 1u) ? 1.0f : 0.0f;
    out4[obase + (size_t)n] = v;
  }
}

extern "C" void kernel_launch(void* const* d_in, const int* in_sizes, int n_in,
                              void* d_out, int out_size, void* d_ws, size_t ws_size,
                              hipStream_t stream) {
  const void* scores = d_in[0];      // dtype autodetected in-kernel
  int* selws = (int*)d_ws;           // 2048 rows x 32 ints = 256 KB
  topk_row<<<dim3(2048), dim3(TPB), 0, stream>>>(scores, selws);
  expand_out<<<dim3(2048), dim3(TPB), 0, stream>>>(selws, (float4*)d_out);
}

// Round 10
// 249.396 us; speedup vs baseline: 1.4016x; 1.0295x over previous
//
#include <hip/hip_runtime.h>

#define TPB 256
#define ROWN 8192
#define CMAX 1024   // per-row candidate cap (r12-r18 proven never hit)
#define EPS_TINY 1.1754943508222875e-38f   // np.finfo(np.float32).tiny

__device__ __forceinline__ unsigned rotl32(unsigned x, int r) {
  return (x << r) | (x >> (32 - r));
}

// threefry2x32, key (0,42), partitionable counters: ctr=(0,idx), bits = x0^x1.
// Verified on-device (r11 decode; r12-r18 absmax 0.0).
__device__ __forceinline__ unsigned tf_pxor(unsigned idx) {
  const unsigned ks0 = 0u, ks1 = 42u, ks2 = 0x1BD11BDAu ^ 0u ^ 42u;
  unsigned x0 = ks0;
  unsigned x1 = idx + ks1;
#define TF4(a,b,cc,d) \
  x0 += x1; x1 = rotl32(x1,(a));  x1 ^= x0; \
  x0 += x1; x1 = rotl32(x1,(b));  x1 ^= x0; \
  x0 += x1; x1 = rotl32(x1,(cc)); x1 ^= x0; \
  x0 += x1; x1 = rotl32(x1,(d));  x1 ^= x0;
  TF4(13,15,26,6)   x0 += ks1; x1 += ks2 + 1u;
  TF4(17,29,16,24)  x0 += ks2; x1 += ks0 + 2u;
  TF4(13,15,26,6)   x0 += ks0; x1 += ks1 + 3u;
  TF4(17,29,16,24)  x0 += ks1; x1 += ks2 + 4u;
  TF4(13,15,26,6)   x0 += ks2; x1 += ks0 + 5u;
#undef TF4
  return x0 ^ x1;
}

// EXACT jax gumbel (precise ocml logf) — candidates only, bit-exact.
__device__ __forceinline__ float gumbel_of(unsigned idx) {
  const unsigned bits = tf_pxor(idx);
  float u = __uint_as_float((bits >> 9) | 0x3f800000u) - 1.0f;
  u = u + EPS_TINY;
  u = fmaxf(EPS_TINY, u);
  return -logf(-logf(u));
}

// APPROX gumbel for the filter pass: |err| <= ~2e-4 (proven r15-r18).
__device__ __forceinline__ float approx_gumbel(unsigned bits) {
  float u = __uint_as_float((bits >> 9) | 0x3f800000u) - 1.0f;
  u = u + EPS_TINY;
  u = fmaxf(EPS_TINY, u);
  float t;
  if (u >= 0.75f) {
    const float v = 1.0f - u;   // exact (Sterbenz)
    t = v * (1.0f + v * (0.5f + v * (0.33333334f + v * (0.25f + v * 0.2f))));
  } else {
    t = -0.69314718f * __log2f(u);
  }
  return -0.69314718f * __log2f(t);
}

// Monotone 16-bit sort key of bf16-truncated float: x<=y => key(x)<=key(y).
// (f finite here: |score|<=16, gumbel in (-5,~30), no NaN/inf.)
__device__ __forceinline__ unsigned key16_of(float x) {
  const unsigned b = __float_as_uint(x) >> 16;
  return (b & 0x8000u) ? (0xFFFFu & ~b) : (b | 0x8000u);
}

// =====================================================================
// Fused kernel: one block per (rep, b, e) ROW. grid=2048, 256 thr.
// r7 byte-for-byte (172.8us best-known; r9's phase-2 reg diet reverted
// as measured-worse) with ONE change: the packed keys fb[16] move from
// registers to LDS kLds[16][256] — explicit private storage. r9 proved
// the spill peak is PHASE 1 (fb pinned across gen+bisect); LDS removes
// those 16 regs from exactly that peak. Each thread reads only its own
// column (lane-stride-1 => conflict-free, no barrier needed for own
// data). candIdx shrinks to u16 -> 18.7 KB LDS/block -> 8 blocks/CU.
// All values/counts/theta/candidate-set identical to r7 (absmax 0.0).
// =====================================================================
__global__ __launch_bounds__(TPB, 8)
void topk_row(const void* __restrict__ scores_raw, int* __restrict__ selws) {
  const int t    = threadIdx.x;
  const int lane = t & 63;
  const int wave = t >> 6;

  // XCD grouping: all 8 rows (4e x 2rep) of input panel b land on one XCD.
  const int i   = blockIdx.x;       // 0..2047
  const int xcd = i & 7;
  const int k   = i >> 3;           // 0..255
  const int e   = k & 3;
  const int q   = k >> 2;           // 0..63
  const int b   = xcd * 32 + (q & 31);
  const int rep = q >> 5;
  const int r   = rep * 1024 + b * 4 + e;
  const unsigned gbase = (unsigned)r * (unsigned)ROWN;

  __shared__ unsigned       kLds[16][TPB];  // 16 KB: 32 keys/thread, 2/word
  __shared__ unsigned short candIdx[CMAX];  // 2 KB (idx < 8192 fits u16)
  __shared__ float redM[4];
  __shared__ float redZ[4];
  __shared__ int   wtot[13][4];
  __shared__ float bV[2][4];
  __shared__ int   bI[2][4];
  __shared__ int   f32flag;

  // ---- input dtype autodetect (4 KB prefix; proven r11-r18) ----
  if (t == 0) f32flag = 0;
  __syncthreads();
  {
    const unsigned* w = (const unsigned*)scores_raw;
    bool bad = false;
#pragma unroll
    for (int p = 0; p < 4; ++p) {
      const unsigned x = w[t + 256 * p];
      const float flo = __uint_as_float((x & 0xFFFFu) << 16);
      const float fhi = __uint_as_float(x & 0xFFFF0000u);
      if (!(fabsf(flo) <= 16.0f) || !(fabsf(fhi) <= 16.0f)) bad = true;
    }
    if (bad) f32flag = 1;
  }
  __syncthreads();
  const bool in_f32 = (f32flag != 0);

  // ================= phase 1: gen -> theta -> compact (single row) ======
  const size_t ebase0 = ((size_t)b * ROWN + (size_t)t) * 4 + (size_t)e;
  float m = -3.4e38f;
  {
    unsigned pair = 0u;
    if (in_f32) {
      const float* sp = (const float*)scores_raw;
#pragma unroll
      for (int j = 0; j < 32; ++j) {
        const float fj = sp[ebase0 + (size_t)(256 * j) * 4]
                       + approx_gumbel(tf_pxor(gbase + (unsigned)(t + 256 * j)));
        m = fmaxf(m, fj);
        const unsigned kk = key16_of(fj);
        if (j & 1) { pair |= kk << 16; kLds[j >> 1][t] = pair; }
        else pair = kk;
      }
    } else {
      const unsigned short* sp = (const unsigned short*)scores_raw;
#pragma unroll
      for (int j = 0; j < 32; ++j) {
        const float fj = __uint_as_float(((unsigned)sp[ebase0 + (size_t)(256 * j) * 4]) << 16)
                       + approx_gumbel(tf_pxor(gbase + (unsigned)(t + 256 * j)));
        m = fmaxf(m, fj);
        const unsigned kk = key16_of(fj);
        if (j & 1) { pair |= kk << 16; kLds[j >> 1][t] = pair; }
        else pair = kk;
      }
    }
  }

  // block max (f32, computed before packing)
#pragma unroll
  for (int off = 32; off >= 1; off >>= 1) m = fmaxf(m, __shfl_xor(m, off));
  if (lane == 0) redM[wave] = m;
  __syncthreads();
  m = fmaxf(fmaxf(redM[0], redM[1]), fmaxf(redM[2], redM[3]));

  // bisect theta33 (12 iters, f32 mids, counts in key domain; keys from LDS)
  float lo = m - 25.0f, hi = m;
#pragma unroll 1
  for (int itb = 0; itb < 12; ++itb) {
    const float mid = 0.5f * (lo + hi);
    const unsigned kmid = key16_of(mid);
    int c = 0;
#pragma unroll
    for (int h = 0; h < 16; ++h) {
      const unsigned w = kLds[h][t];
      c += ((w & 0xFFFFu) > kmid) ? 1 : 0;
      c += ((w >> 16) > kmid) ? 1 : 0;
    }
#pragma unroll
    for (int off = 32; off >= 1; off >>= 1) c += __shfl_xor(c, off);
    if (lane == 0) wtot[itb][wave] = c;
    __syncthreads();
    const int tot = wtot[itb][0] + wtot[itb][1] + wtot[itb][2] + wtot[itb][3];
    if (tot >= 33) lo = mid; else hi = mid;
  }
  const float theta = lo - 2.34f;          // lo < f*_(33) via monotone key
  const unsigned ktheta = key16_of(theta); // compact predicate: key >= ktheta

  // compact candidate indices (deterministic prefix order, >= superset)
  int cj = 0;
#pragma unroll
  for (int h = 0; h < 16; ++h) {
    const unsigned w = kLds[h][t];
    cj += ((w & 0xFFFFu) >= ktheta) ? 1 : 0;
    cj += ((w >> 16) >= ktheta) ? 1 : 0;
  }
  int incv = cj;
#pragma unroll
  for (int off = 1; off < 64; off <<= 1) {
    const int v = __shfl_up(incv, off);
    if (lane >= off) incv += v;
  }
  if (lane == 63) wtot[12][wave] = incv;
  __syncthreads();
  int base = 0;
  for (int w = 0; w < wave; ++w) base += wtot[12][w];
  int cnt = wtot[12][0] + wtot[12][1] + wtot[12][2] + wtot[12][3];
  if (cnt > CMAX) cnt = CMAX;
  int o = base + incv - cj;
#pragma unroll
  for (int h = 0; h < 16; ++h) {
    const unsigned w = kLds[h][t];
    if ((w & 0xFFFFu) >= ktheta) {           // j = 2h
      if (o < CMAX) candIdx[o] = (unsigned short)(t + 256 * (2 * h));
      ++o;
    }
    if ((w >> 16) >= ktheta) {               // j = 2h+1
      if (o < CMAX) candIdx[o] = (unsigned short)(t + 256 * (2 * h + 1));
      ++o;
    }
  }
  __syncthreads();   // candIdx visible to whole block

  // ================= phase 2: block-wide dynamics (4 chunks of 256) =====
  float cfr[4], khr[4];
  int   idxr[4];
#pragma unroll
  for (int p = 0; p < 4; ++p) {
    cfr[p] = -3.0e38f; khr[p] = -3.0e38f; idxr[p] = 0x7FFFFFFF;
    if (256 * p < cnt) {               // block-uniform chunk skip
      const int ci = t + 256 * p;
      if (ci < cnt) {
        const int n = (int)candIdx[ci];
        const size_t ei = ((size_t)b * ROWN + (size_t)n) * 4 + (size_t)e;
        float sc;
        if (in_f32) sc = ((const float*)scores_raw)[ei];
        else sc = __uint_as_float(((unsigned)((const unsigned short*)scores_raw)[ei]) << 16);
        cfr[p] = sc + gumbel_of(gbase + (unsigned)n);   // bit-exact
        khr[p] = 0.0f;
        idxr[p] = n;
      }
    }
  }

  // 32 dynamics iterations; fast-math branchless body (r6/r7, absmax 0.0).
#pragma unroll 1
  for (int it = 0; it < 32; ++it) {
    float m2 = -3.4e38f;
#pragma unroll
    for (int p = 0; p < 4; ++p)
      if (256 * p < cnt) m2 = fmaxf(m2, cfr[p]);
#pragma unroll
    for (int off = 32; off >= 1; off >>= 1) m2 = fmaxf(m2, __shfl_xor(m2, off));
    if (lane == 0) redM[wave] = m2;
    __syncthreads();
    m2 = fmaxf(fmaxf(redM[0], redM[1]), fmaxf(redM[2], redM[3]));

    float ek[4];
    float Z = 0.0f;
#pragma unroll
    for (int p = 0; p < 4; ++p) {
      float ev = 0.0f;
      if (256 * p < cnt) {
        // filler cfr=-3e38: (cfr-m2)*10 -> -inf -> ev = 0 (exact no-op)
        ev = __expf((cfr[p] - m2) * 10.0f);
        Z += ev;
      }
      ek[p] = ev;
    }
#pragma unroll
    for (int off = 32; off >= 1; off >>= 1) Z += __shfl_xor(Z, off);
    if (lane == 0) redZ[wave] = Z;
    __syncthreads();
    Z = (redZ[0] + redZ[1]) + (redZ[2] + redZ[3]);   // fixed deterministic order

    const float rz = __builtin_amdgcn_rcpf(Z);       // Z in [1,cnt]; ~1e-7 rel
#pragma unroll
    for (int p = 0; p < 4; ++p) {
      if (256 * p < cnt) {
        const float pp = ek[p] * rz;                 // 0 for inactive lanes
        khr[p] += pp;                                // += 0 is bitwise no-op
        cfr[p] += __logf(fmaxf(1.0f - pp, EPS_TINY));
      }
    }
  }

  // top-32 of khot, lowest-n tie-break, block-wide (double-buffered slots)
#pragma unroll 1
  for (int pass = 0; pass < 32; ++pass) {
    float bv = -3.4e38f; int bi = 0x7FFFFFFF;
#pragma unroll
    for (int p = 0; p < 4; ++p) {
      if (256 * p < cnt) {
        const float v = khr[p]; const int ix = idxr[p];
        if (v > bv || (v == bv && ix < bi)) { bv = v; bi = ix; }
      }
    }
#pragma unroll
    for (int off = 32; off >= 1; off >>= 1) {
      const float ov = __shfl_xor(bv, off);
      const int   oi = __shfl_xor(bi, off);
      if (ov > bv || (ov == bv && oi < bi)) { bv = ov; bi = oi; }
    }
    if (lane == 0) { bV[pass & 1][wave] = bv; bI[pass & 1][wave] = bi; }
    __syncthreads();
#pragma unroll
    for (int w = 0; w < 4; ++w) {
      const float ov = bV[pass & 1][w]; const int oi = bI[pass & 1][w];
      if (ov > bv || (ov == bv && oi < bi)) { bv = ov; bi = oi; }
    }
    if (t == 0) selws[r * 32 + pass] = bi;
#pragma unroll
    for (int p = 0; p < 4; ++p)
      if (256 * p < cnt && idxr[p] == bi) khr[p] = -3.0e38f;
  }
}

// =====================================================================
// Kernel 2: bitmap expand -> coalesced float4 slab (unchanged, proven).
// =====================================================================
__global__ __launch_bounds__(TPB)
void expand_out(const int* __restrict__ selws, float4* __restrict__ out4) {
  const int t   = threadIdx.x;
  const int blk = blockIdx.x;        // 0..2047
  const int grp = blk >> 2;          // rep*256 + b
  const int s   = blk & 3;           // n-slice of 2048
  const int rep = grp >> 8;
  const int b   = grp & 255;

  __shared__ unsigned ebm[4 * 256];  // 4 e-planes x 8192 bits
#pragma unroll
  for (int p = 0; p < 4; ++p) ebm[t + 256 * p] = 0u;
  __syncthreads();
  if (t < 4) {
    const int r = rep * 1024 + b * 4 + t;
#pragma unroll 1
    for (int p = 0; p < 32; ++p) {
      const int ix = selws[r * 32 + p];
      ebm[t * 256 + (ix >> 5)] |= (1u << (ix & 31));
    }
  }
  __syncthreads();

  const size_t obase = (size_t)grp * ROWN;
#pragma unroll
  for (int j = 0; j < 8; ++j) {
    const int n = s * 2048 + t + 256 * j;
    float4 v;
    v.x = ((ebm[0 * 256 + (n >> 5)] >> (n & 31)) & 1u) ? 1.0f : 0.0f;
    v.y = ((ebm[1 * 256 + (n >> 5)] >> (n & 31)) & 1u) ? 1.0f : 0.0f;
    v.z = ((ebm[2 * 256 + (n >> 5)] >> (n & 31)) & 1u) ? 1.0f : 0.0f;
    v.w = ((ebm[3 * 256 + (n >> 5)] >> (n & 31)) & 1u) ? 1.0f : 0.0f;
    out4[obase + (size_t)n] = v;
  }
}

extern "C" void kernel_launch(void* const* d_in, const int* in_sizes, int n_in,
                              void* d_out, int out_size, void* d_ws, size_t ws_size,
                              hipStream_t stream) {
  const void* scores = d_in[0];      // dtype autodetected in-kernel
  int* selws = (int*)d_ws;           // 2048 rows x 32 ints = 256 KB
  topk_row<<<dim3(2048), dim3(TPB), 0, stream>>>(scores, selws);
  expand_out<<<dim3(2048), dim3(TPB), 0, stream>>>(selws, (float4*)d_out);
}

// Round 11
// 231.520 us; speedup vs baseline: 1.5098x; 1.0772x over previous
//
#include <hip/hip_runtime.h>

#define TPB 256
#define ROWN 8192
#define CMAX 1024   // per-row candidate cap (r12-r18 proven never hit)
#define EPS_TINY 1.1754943508222875e-38f   // np.finfo(np.float32).tiny

__device__ __forceinline__ unsigned rotl32(unsigned x, int r) {
  return (x << r) | (x >> (32 - r));
}

// threefry2x32, key (0,42), partitionable counters: ctr=(0,idx), bits = x0^x1.
// Verified on-device (r11 decode; r12-r18 absmax 0.0).
__device__ __forceinline__ unsigned tf_pxor(unsigned idx) {
  const unsigned ks0 = 0u, ks1 = 42u, ks2 = 0x1BD11BDAu ^ 0u ^ 42u;
  unsigned x0 = ks0;
  unsigned x1 = idx + ks1;
#define TF4(a,b,cc,d) \
  x0 += x1; x1 = rotl32(x1,(a));  x1 ^= x0; \
  x0 += x1; x1 = rotl32(x1,(b));  x1 ^= x0; \
  x0 += x1; x1 = rotl32(x1,(cc)); x1 ^= x0; \
  x0 += x1; x1 = rotl32(x1,(d));  x1 ^= x0;
  TF4(13,15,26,6)   x0 += ks1; x1 += ks2 + 1u;
  TF4(17,29,16,24)  x0 += ks2; x1 += ks0 + 2u;
  TF4(13,15,26,6)   x0 += ks0; x1 += ks1 + 3u;
  TF4(17,29,16,24)  x0 += ks1; x1 += ks2 + 4u;
  TF4(13,15,26,6)   x0 += ks2; x1 += ks0 + 5u;
#undef TF4
  return x0 ^ x1;
}

// EXACT jax gumbel (precise ocml logf) — candidates only, bit-exact.
__device__ __forceinline__ float gumbel_of(unsigned idx) {
  const unsigned bits = tf_pxor(idx);
  float u = __uint_as_float((bits >> 9) | 0x3f800000u) - 1.0f;
  u = u + EPS_TINY;
  u = fmaxf(EPS_TINY, u);
  return -logf(-logf(u));
}

// APPROX gumbel for the filter pass: |err| <= ~2e-4 (proven r15-r18).
__device__ __forceinline__ float approx_gumbel(unsigned bits) {
  float u = __uint_as_float((bits >> 9) | 0x3f800000u) - 1.0f;
  u = u + EPS_TINY;
  u = fmaxf(EPS_TINY, u);
  float t;
  if (u >= 0.75f) {
    const float v = 1.0f - u;   // exact (Sterbenz)
    t = v * (1.0f + v * (0.5f + v * (0.33333334f + v * (0.25f + v * 0.2f))));
  } else {
    t = -0.69314718f * __log2f(u);
  }
  return -0.69314718f * __log2f(t);
}

// Monotone 16-bit sort key of bf16-truncated float: x<=y => key(x)<=key(y).
// (f finite here: |score|<=16, gumbel in (-5,~30), no NaN/inf.)
__device__ __forceinline__ unsigned key16_of(float x) {
  const unsigned b = __float_as_uint(x) >> 16;
  return (b & 0x8000u) ? (0xFFFFu & ~b) : (b | 0x8000u);
}

// =====================================================================
// Fused kernel: one block per (rep, b, e) ROW. grid=2048, 256 thr.
// r10 base (spill-free, keys in LDS, absmax 0.0 / 180us) + TWO cuts of
// the block-wide reduction cost (r10 proved the structure is
// reduction/barrier-bound, not spill-bound):
//  1. STALE-MAX: cfr is non-increasing (+= log(1-p) <= 0), so any past
//     max upper-bounds all later cfr. Recompute m2 only every 4th iter;
//     softmax is shift-invariant (ratios exact mod <=1e-7 rounding);
//     drift <=~2 in cf (20 in exp-arg) vs the -87 underflow cliff.
//     Kills 24 max-reduces + 24 barriers. redZ parity-double-buffered.
//  2. WAVE-LOCAL SELECTION: khot -> LDS (reusing dead key buffer), one
//     barrier, waves 1-3 exit; wave 0 runs the 32 argmax passes with a
//     (v,n,ci) shfl tree, zero barriers. Tie-break on original n —
//     winner sequence identical to the block-wide version.
// =====================================================================
__global__ __launch_bounds__(TPB, 8)
void topk_row(const void* __restrict__ scores_raw, int* __restrict__ selws) {
  const int t    = threadIdx.x;
  const int lane = t & 63;
  const int wave = t >> 6;

  // XCD grouping: all 8 rows (4e x 2rep) of input panel b land on one XCD.
  const int i   = blockIdx.x;       // 0..2047
  const int xcd = i & 7;
  const int k   = i >> 3;           // 0..255
  const int e   = k & 3;
  const int q   = k >> 2;           // 0..63
  const int b   = xcd * 32 + (q & 31);
  const int rep = q >> 5;
  const int r   = rep * 1024 + b * 4 + e;
  const unsigned gbase = (unsigned)r * (unsigned)ROWN;

  __shared__ unsigned       kLds[16][TPB];  // 16 KB keys; reused as khLds
  __shared__ unsigned short candIdx[CMAX];  // 2 KB (idx < 8192 fits u16)
  __shared__ float redM[4];
  __shared__ float redZ[2][4];              // parity double-buffer
  __shared__ int   wtot[13][4];
  __shared__ int   f32flag;

  // ---- input dtype autodetect (4 KB prefix; proven r11-r18) ----
  if (t == 0) f32flag = 0;
  __syncthreads();
  {
    const unsigned* w = (const unsigned*)scores_raw;
    bool bad = false;
#pragma unroll
    for (int p = 0; p < 4; ++p) {
      const unsigned x = w[t + 256 * p];
      const float flo = __uint_as_float((x & 0xFFFFu) << 16);
      const float fhi = __uint_as_float(x & 0xFFFF0000u);
      if (!(fabsf(flo) <= 16.0f) || !(fabsf(fhi) <= 16.0f)) bad = true;
    }
    if (bad) f32flag = 1;
  }
  __syncthreads();
  const bool in_f32 = (f32flag != 0);

  // ================= phase 1: gen -> theta -> compact (single row) ======
  const size_t ebase0 = ((size_t)b * ROWN + (size_t)t) * 4 + (size_t)e;
  float m = -3.4e38f;
  {
    unsigned pair = 0u;
    if (in_f32) {
      const float* sp = (const float*)scores_raw;
#pragma unroll
      for (int j = 0; j < 32; ++j) {
        const float fj = sp[ebase0 + (size_t)(256 * j) * 4]
                       + approx_gumbel(tf_pxor(gbase + (unsigned)(t + 256 * j)));
        m = fmaxf(m, fj);
        const unsigned kk = key16_of(fj);
        if (j & 1) { pair |= kk << 16; kLds[j >> 1][t] = pair; }
        else pair = kk;
      }
    } else {
      const unsigned short* sp = (const unsigned short*)scores_raw;
#pragma unroll
      for (int j = 0; j < 32; ++j) {
        const float fj = __uint_as_float(((unsigned)sp[ebase0 + (size_t)(256 * j) * 4]) << 16)
                       + approx_gumbel(tf_pxor(gbase + (unsigned)(t + 256 * j)));
        m = fmaxf(m, fj);
        const unsigned kk = key16_of(fj);
        if (j & 1) { pair |= kk << 16; kLds[j >> 1][t] = pair; }
        else pair = kk;
      }
    }
  }

  // block max (f32, computed before packing)
#pragma unroll
  for (int off = 32; off >= 1; off >>= 1) m = fmaxf(m, __shfl_xor(m, off));
  if (lane == 0) redM[wave] = m;
  __syncthreads();
  m = fmaxf(fmaxf(redM[0], redM[1]), fmaxf(redM[2], redM[3]));

  // bisect theta33 (12 iters, f32 mids, counts in key domain; keys from LDS)
  float lo = m - 25.0f, hi = m;
#pragma unroll 1
  for (int itb = 0; itb < 12; ++itb) {
    const float mid = 0.5f * (lo + hi);
    const unsigned kmid = key16_of(mid);
    int c = 0;
#pragma unroll
    for (int h = 0; h < 16; ++h) {
      const unsigned w = kLds[h][t];
      c += ((w & 0xFFFFu) > kmid) ? 1 : 0;
      c += ((w >> 16) > kmid) ? 1 : 0;
    }
#pragma unroll
    for (int off = 32; off >= 1; off >>= 1) c += __shfl_xor(c, off);
    if (lane == 0) wtot[itb][wave] = c;
    __syncthreads();
    const int tot = wtot[itb][0] + wtot[itb][1] + wtot[itb][2] + wtot[itb][3];
    if (tot >= 33) lo = mid; else hi = mid;
  }
  const float theta = lo - 2.34f;          // lo < f*_(33) via monotone key
  const unsigned ktheta = key16_of(theta); // compact predicate: key >= ktheta

  // compact candidate indices (deterministic prefix order, >= superset)
  int cj = 0;
#pragma unroll
  for (int h = 0; h < 16; ++h) {
    const unsigned w = kLds[h][t];
    cj += ((w & 0xFFFFu) >= ktheta) ? 1 : 0;
    cj += ((w >> 16) >= ktheta) ? 1 : 0;
  }
  int incv = cj;
#pragma unroll
  for (int off = 1; off < 64; off <<= 1) {
    const int v = __shfl_up(incv, off);
    if (lane >= off) incv += v;
  }
  if (lane == 63) wtot[12][wave] = incv;
  __syncthreads();
  int base = 0;
  for (int w = 0; w < wave; ++w) base += wtot[12][w];
  int cnt = wtot[12][0] + wtot[12][1] + wtot[12][2] + wtot[12][3];
  if (cnt > CMAX) cnt = CMAX;
  int o = base + incv - cj;
#pragma unroll
  for (int h = 0; h < 16; ++h) {
    const unsigned w = kLds[h][t];
    if ((w & 0xFFFFu) >= ktheta) {           // j = 2h
      if (o < CMAX) candIdx[o] = (unsigned short)(t + 256 * (2 * h));
      ++o;
    }
    if ((w >> 16) >= ktheta) {               // j = 2h+1
      if (o < CMAX) candIdx[o] = (unsigned short)(t + 256 * (2 * h + 1));
      ++o;
    }
  }
  __syncthreads();   // candIdx visible to whole block (kLds keys now dead)

  // ================= phase 2: block-wide dynamics (4 chunks of 256) =====
  float cfr[4], khr[4];
#pragma unroll
  for (int p = 0; p < 4; ++p) {
    cfr[p] = -3.0e38f; khr[p] = -3.0e38f;
    if (256 * p < cnt) {               // block-uniform chunk skip
      const int ci = t + 256 * p;
      if (ci < cnt) {
        const int n = (int)candIdx[ci];
        const size_t ei = ((size_t)b * ROWN + (size_t)n) * 4 + (size_t)e;
        float sc;
        if (in_f32) sc = ((const float*)scores_raw)[ei];
        else sc = __uint_as_float(((unsigned)((const unsigned short*)scores_raw)[ei]) << 16);
        cfr[p] = sc + gumbel_of(gbase + (unsigned)n);   // bit-exact
        khr[p] = 0.0f;
      }
    }
  }

  // 32 dynamics iterations; fast-math branchless body (absmax 0.0 r6-r10).
  // Stale-max anchor recomputed every 4th iter (valid upper bound: cfr
  // non-increasing). One barrier/iter (Z, parity-buffered) + 8 max barriers.
  float m2 = 0.0f;
#pragma unroll 1
  for (int it = 0; it < 32; ++it) {
    if ((it & 3) == 0) {
      float mm = -3.4e38f;
#pragma unroll
      for (int p = 0; p < 4; ++p)
        if (256 * p < cnt) mm = fmaxf(mm, cfr[p]);
#pragma unroll
      for (int off = 32; off >= 1; off >>= 1) mm = fmaxf(mm, __shfl_xor(mm, off));
      if (lane == 0) redM[wave] = mm;
      __syncthreads();
      m2 = fmaxf(fmaxf(redM[0], redM[1]), fmaxf(redM[2], redM[3]));
    }

    float ek[4];
    float Z = 0.0f;
#pragma unroll
    for (int p = 0; p < 4; ++p) {
      float ev = 0.0f;
      if (256 * p < cnt) {
        // filler cfr=-3e38: (cfr-m2)*10 -> -inf -> ev = 0 (exact no-op)
        ev = __expf((cfr[p] - m2) * 10.0f);
        Z += ev;
      }
      ek[p] = ev;
    }
#pragma unroll
    for (int off = 32; off >= 1; off >>= 1) Z += __shfl_xor(Z, off);
    if (lane == 0) redZ[it & 1][wave] = Z;
    __syncthreads();
    Z = (redZ[it & 1][0] + redZ[it & 1][1]) + (redZ[it & 1][2] + redZ[it & 1][3]);

    const float rz = __builtin_amdgcn_rcpf(Z);       // Z > 0; ~1e-7 rel
#pragma unroll
    for (int p = 0; p < 4; ++p) {
      if (256 * p < cnt) {
        const float pp = ek[p] * rz;                 // 0 for inactive lanes
        khr[p] += pp;                                // += 0 is bitwise no-op
        cfr[p] += __logf(fmaxf(1.0f - pp, EPS_TINY));
      }
    }
  }

  // ============== selection: wave-local on wave 0, zero barriers =========
  float* khLds = (float*)&kLds[0][0];   // reuse dead key buffer (4 KB used)
#pragma unroll
  for (int p = 0; p < 4; ++p) {
    if (256 * p < cnt) {
      const int ci = t + 256 * p;
      if (ci < cnt) khLds[ci] = khr[p];
    }
  }
  __syncthreads();   // LAST barrier
  if (wave != 0) return;

  const int nch = (cnt + 63) >> 6;
#pragma unroll 1
  for (int pass = 0; pass < 32; ++pass) {
    float bv = -3.4e38f; int bn = 0x7FFFFFFF; int bci = 0;
#pragma unroll 1
    for (int c = 0; c < nch; ++c) {
      const int ci = lane + 64 * c;
      if (ci < cnt) {
        const float v = khLds[ci];
        const int  n = (int)candIdx[ci];
        if (v > bv || (v == bv && n < bn)) { bv = v; bn = n; bci = ci; }
      }
    }
#pragma unroll
    for (int off = 32; off >= 1; off >>= 1) {
      const float ov = __shfl_xor(bv, off);
      const int   on = __shfl_xor(bn, off);
      const int   oc = __shfl_xor(bci, off);
      if (ov > bv || (ov == bv && on < bn)) { bv = ov; bn = on; bci = oc; }
    }
    if (lane == 0) {
      selws[r * 32 + pass] = bn;
      khLds[bci] = -3.0e38f;     // remove winner (same-wave DS ordering)
    }
  }
}

// =====================================================================
// Kernel 2: bitmap expand -> coalesced float4 slab (unchanged, proven).
// =====================================================================
__global__ __launch_bounds__(TPB)
void expand_out(const int* __restrict__ selws, float4* __restrict__ out4) {
  const int t   = threadIdx.x;
  const int blk = blockIdx.x;        // 0..2047
  const int grp = blk >> 2;          // rep*256 + b
  const int s   = blk & 3;           // n-slice of 2048
  const int rep = grp >> 8;
  const int b   = grp & 255;

  __shared__ unsigned ebm[4 * 256];  // 4 e-planes x 8192 bits
#pragma unroll
  for (int p = 0; p < 4; ++p) ebm[t + 256 * p] = 0u;
  __syncthreads();
  if (t < 4) {
    const int r = rep * 1024 + b * 4 + t;
#pragma unroll 1
    for (int p = 0; p < 32; ++p) {
      const int ix = selws[r * 32 + p];
      ebm[t * 256 + (ix >> 5)] |= (1u << (ix & 31));
    }
  }
  __syncthreads();

  const size_t obase = (size_t)grp * ROWN;
#pragma unroll
  for (int j = 0; j < 8; ++j) {
    const int n = s * 2048 + t + 256 * j;
    float4 v;
    v.x = ((ebm[0 * 256 + (n >> 5)] >> (n & 31)) & 1u) ? 1.0f : 0.0f;
    v.y = ((ebm[1 * 256 + (n >> 5)] >> (n & 31)) & 1u) ? 1.0f : 0.0f;
    v.z = ((ebm[2 * 256 + (n >> 5)] >> (n & 31)) & 1u) ? 1.0f : 0.0f;
    v.w = ((ebm[3 * 256 + (n >> 5)] >> (n & 31)) & 1u) ? 1.0f : 0.0f;
    out4[obase + (size_t)n] = v;
  }
}

extern "C" void kernel_launch(void* const* d_in, const int* in_sizes, int n_in,
                              void* d_out, int out_size, void* d_ws, size_t ws_size,
                              hipStream_t stream) {
  const void* scores = d_in[0];      // dtype autodetected in-kernel
  int* selws = (int*)d_ws;           // 2048 rows x 32 ints = 256 KB
  topk_row<<<dim3(2048), dim3(TPB), 0, stream>>>(scores, selws);
  expand_out<<<dim3(2048), dim3(TPB), 0, stream>>>(selws, (float4*)d_out);
}